// Round 7
// baseline (9360.109 us; speedup 1.0000x reference)
//
#include <hip/hip_runtime.h>
#include <hip/hip_fp16.h>
#include <string.h>

// Problem constants (match reference)
constexpr int B = 64, T = 512, I = 512, H = 512, G = 2048; // G = 4*H

typedef _Float16 half8 __attribute__((ext_vector_type(8)));
typedef float floatx4 __attribute__((ext_vector_type(4)));

// ---------------------------------------------------------------------------
// Phase 1: xg[t][g][b] = sum_i x[b][t][i] * W_ih[g][i] + (b_ih[g] + b_hh[g])
// stored as f16. (unchanged, proven)
// ---------------------------------------------------------------------------
__global__ __launch_bounds__(256, 2) void xg_gemm(
    const float* __restrict__ x,     // [B][T][I]
    const float* __restrict__ W_ih,  // [G][I]
    const float* __restrict__ b_ih,
    const float* __restrict__ b_hh,
    _Float16* __restrict__ xg)       // [T][G][B]
{
    const int tid  = threadIdx.x;
    const int wave = tid >> 6, lane = tid & 63;
    const int quad = lane >> 4, col = lane & 15;
    const int rowA = blockIdx.x * 128 + wave * 16;
    const int rowB = rowA + 64;

    __shared__ __align__(16) _Float16 xs[64][264];

    half8 wfA[16], wfB[16];
    {
        const float* wpA = W_ih + (size_t)(rowA + col) * I;
        const float* wpB = W_ih + (size_t)(rowB + col) * I;
#pragma unroll
        for (int kc = 0; kc < 16; ++kc) {
            half8 vA, vB;
#pragma unroll
            for (int j = 0; j < 8; ++j) {
                vA[j] = (_Float16)wpA[kc * 32 + quad * 8 + j];
                vB[j] = (_Float16)wpB[kc * 32 + quad * 8 + j];
            }
            wfA[kc] = vA; wfB[kc] = vB;
        }
    }
    float biasA[4], biasB[4];
#pragma unroll
    for (int r = 0; r < 4; ++r) {
        biasA[r] = b_ih[rowA + quad * 4 + r] + b_hh[rowA + quad * 4 + r];
        biasB[r] = b_ih[rowB + quad * 4 + r] + b_hh[rowB + quad * 4 + r];
    }

    for (int ti = 0; ti < 4; ++ti) {
        const int t = blockIdx.y * 4 + ti;
        floatx4 accA[4], accB[4];
#pragma unroll
        for (int nt = 0; nt < 4; ++nt) {
            accA[nt] = (floatx4){0.f, 0.f, 0.f, 0.f};
            accB[nt] = (floatx4){0.f, 0.f, 0.f, 0.f};
        }

        for (int hfl = 0; hfl < 2; ++hfl) {
            __syncthreads();
#pragma unroll 4
            for (int c = 0; c < 16; ++c) {
                int idx = c * 256 + tid;
                int row = idx >> 6;
                int kk  = (idx & 63) * 4;
                const float4 v = *(const float4*)(x + ((size_t)row * T + t) * I + hfl * 256 + kk);
                xs[row][kk + 0] = (_Float16)v.x;
                xs[row][kk + 1] = (_Float16)v.y;
                xs[row][kk + 2] = (_Float16)v.z;
                xs[row][kk + 3] = (_Float16)v.w;
            }
            __syncthreads();
#pragma unroll
            for (int kc = 0; kc < 8; ++kc) {
#pragma unroll
                for (int nt = 0; nt < 4; ++nt) {
                    const half8 bfr = *(const half8*)&xs[nt * 16 + col][kc * 32 + quad * 8];
                    accA[nt] = __builtin_amdgcn_mfma_f32_16x16x32_f16(
                        wfA[hfl * 8 + kc], bfr, accA[nt], 0, 0, 0);
                    accB[nt] = __builtin_amdgcn_mfma_f32_16x16x32_f16(
                        wfB[hfl * 8 + kc], bfr, accB[nt], 0, 0, 0);
                }
            }
        }
#pragma unroll
        for (int nt = 0; nt < 4; ++nt) {
            int b = nt * 16 + col;
#pragma unroll
            for (int r = 0; r < 4; ++r) {
                xg[((size_t)t * G + rowA + quad * 4 + r) * B + b] = (_Float16)(accA[nt][r] + biasA[r]);
                xg[((size_t)t * G + rowB + quad * 4 + r) * B + b] = (_Float16)(accB[nt][r] + biasB[r]);
            }
        }
    }
}

// ---------------------------------------------------------------------------
// Phase 2: persistent recurrence, SELF-VALIDATING records + BULK spin.
//
// Calibrated model (R0-R6): agent/LLC round-trip (sc1, bypasses L1+L2, IF
// fabric to MALL) ~= 0.9-1.2us. R3/R5's chain = store-ack RT + flag RT +
// detect RT + payload RT ~= 4 RT = 5.9us/step (matches). R4's per-kc spins
// with window loads issued between checks forced 16 serial RTs = 11.5us/step
// (matches). Burner experiment (R6) falsified clock throttling.
//
// This design cuts the chain to ~1.5-2.5 RT:
//   record  = u64 {2 x f16 h, u32 epoch tag} (8B atomic: single-copy,
//             proven correct in R4; no R2 16B tearing)
//   producer: gates -> 2 fire-and-forget u64 stores. No ack, no flag, no
//             __syncthreads anywhere in the loop (waves free-run).
//   consumer: issue ALL 32 record loads in parallel -> one wait -> check all
//             tags -> bulk-reload while any stale. Each round = 1 RT (not 16:
//             R4's bug was per-kc serialized waits). Detection IS the load.
//   xg      : issue+retire-pinned OUTSIDE the spin (R5 mechanism) so spin
//             rounds contain only record loads.
//
// Freeze induction (as R4, correctness-proven there): block X overwrites its
// tag-(t+1) records (publishing tag t+3, same parity) only after consuming
// all tag-(t+2) records; any wave publishes its t+2 records only after its
// lanes consumed all tag-(t+1) records. So no record is overwritten while a
// consumer can still legitimately read it; tags are monotonic; torn reads
// excluded by 8B atomicity.
// ---------------------------------------------------------------------------
__global__ __launch_bounds__(256, 1) void lstm_rec(
    const float* __restrict__ h0,    // [B][H]
    const float* __restrict__ c0,    // [B][H]
    const float* __restrict__ W_hh,  // [G][H]
    const _Float16* __restrict__ xg, // [T][G][B]
    unsigned long long* __restrict__ rec, // [2][4][16][256] u64, zeroed
    float* __restrict__ out)         // [B][T][H] ++ hT[B][H] ++ cT[B][H]
{
    const int blk  = blockIdx.x;
    const int bg   = blk & 3;        // batch group (16 batches)
    const int hg   = blk >> 2;       // H slice (32 h-indices)
    const int tid  = threadIdx.x;
    const int wave = tid >> 6, lane = tid & 63;
    const int quad = lane >> 4, col = lane & 15;

    const int bglob = bg * 16 + col;       // this lane's batch
    const int hbase = hg * 32 + wave * 8;  // this wave's 8 h-indices

    // A-fragment rows (m = col): tile0 = [i(8), f(8)], tile1 = [g(8), o(8)]
    int arow0 = (col < 8) ? (hbase + col) : (512 + hbase + col - 8);
    int arow1 = arow0 + 1024;
    half8 wf0[16], wf1[16];
#pragma unroll
    for (int kc = 0; kc < 16; ++kc) {
        const float* p0 = W_hh + (size_t)arow0 * H + kc * 32 + quad * 8;
        const float* p1 = W_hh + (size_t)arow1 * H + kc * 32 + quad * 8;
        half8 v0, v1;
#pragma unroll
        for (int j = 0; j < 8; ++j) { v0[j] = (_Float16)p0[j]; v1[j] = (_Float16)p1[j]; }
        wf0[kc] = v0; wf1[kc] = v1;
    }

    // C rows this lane holds (lr = quad*4+r): xg row indices
    int xrow0[4], xrow1[4];
#pragma unroll
    for (int r = 0; r < 4; ++r) {
        int lr = quad * 4 + r;
        xrow0[r] = (lr < 8) ? (hbase + lr) : (512 + hbase + lr - 8);
        xrow1[r] = xrow0[r] + 1024;
    }

    // After xor-32 exchange this lane updates h-index hbase + (quad&1)*4 + r
    float c[4];
#pragma unroll
    for (int r = 0; r < 4; ++r)
        c[r] = c0[(size_t)bglob * H + hbase + (quad & 1) * 4 + r];

    // record buffers (u64 units); group block = 16 batches x 256 pairs
    unsigned long long* rb0 = rec + (size_t)(0 * 4 + bg) * 16 * 256;
    unsigned long long* rb1 = rec + (size_t)(1 * 4 + bg) * 16 * 256;

    // producer: lanes quad<2 own pair records mybase, mybase+1 (4 f16)
    const int myp    = (hbase + (quad & 1) * 4) >> 1;
    const int mybase = col * 256 + myp;

    // consumer: records cbase + kc*16 + {0..3} = h[col][kc*32+quad*8+0..7]
    const int cbase = col * 256 + quad * 4;

    // init: publish h0 with tag 1 (fire-and-forget)
    if (quad < 2) {
        _Float16 a01[2] = {(_Float16)h0[(size_t)bglob * H + hbase + (quad & 1) * 4 + 0],
                           (_Float16)h0[(size_t)bglob * H + hbase + (quad & 1) * 4 + 1]};
        _Float16 a23[2] = {(_Float16)h0[(size_t)bglob * H + hbase + (quad & 1) * 4 + 2],
                           (_Float16)h0[(size_t)bglob * H + hbase + (quad & 1) * 4 + 3]};
        unsigned lo0, lo1;
        __builtin_memcpy(&lo0, a01, 4);
        __builtin_memcpy(&lo1, a23, 4);
        __hip_atomic_store(rb0 + mybase,     (unsigned long long)lo0 | (1ull << 32),
                           __ATOMIC_RELAXED, __HIP_MEMORY_SCOPE_AGENT);
        __hip_atomic_store(rb0 + mybase + 1, (unsigned long long)lo1 | (1ull << 32),
                           __ATOMIC_RELAXED, __HIP_MEMORY_SCOPE_AGENT);
    }

    // xg(t=0): issue AND retire before the first spin (vmcnt decouple, R5)
    float xp0[4], xp1[4];
#pragma unroll
    for (int r = 0; r < 4; ++r) {
        xp0[r] = (float)xg[(size_t)xrow0[r] * B + bglob];
        xp1[r] = (float)xg[(size_t)xrow1[r] * B + bglob];
    }
    asm volatile("" : "+v"(xp0[0]), "+v"(xp0[1]), "+v"(xp0[2]), "+v"(xp0[3]),
                      "+v"(xp1[0]), "+v"(xp1[1]), "+v"(xp1[2]), "+v"(xp1[3]) :: "memory");

    float hh[4] = {0.f, 0.f, 0.f, 0.f};

    for (int t = 0; t < T; ++t) {
        unsigned long long* rcur = (t & 1) ? rb1 : rb0;
        unsigned long long* rnxt = (t & 1) ? rb0 : rb1;
        const unsigned tg = (unsigned)(t + 1);

        // ---- BULK spin: all 32 loads in flight per round; 1 RT per round
        unsigned long long v[16][4];
#pragma unroll
        for (int kc = 0; kc < 16; ++kc)
#pragma unroll
            for (int i = 0; i < 4; ++i)
                v[kc][i] = __hip_atomic_load(rcur + cbase + kc * 16 + i,
                                             __ATOMIC_RELAXED, __HIP_MEMORY_SCOPE_AGENT);
        for (;;) {
            unsigned bad = 0u;
#pragma unroll
            for (int kc = 0; kc < 16; ++kc)
#pragma unroll
                for (int i = 0; i < 4; ++i)
                    bad |= (unsigned)(v[kc][i] >> 32) ^ tg;
            if (__all(bad == 0u)) break;
#pragma unroll
            for (int kc = 0; kc < 16; ++kc)
#pragma unroll
                for (int i = 0; i < 4; ++i)
                    v[kc][i] = __hip_atomic_load(rcur + cbase + kc * 16 + i,
                                                 __ATOMIC_RELAXED, __HIP_MEMORY_SCOPE_AGENT);
        }

        // ---- MFMA: payload already in registers; 4 independent 8-deep chains
        floatx4 a0a = (floatx4){0.f, 0.f, 0.f, 0.f}, a0b = a0a;
        floatx4 a1a = a0a, a1b = a0a;
#pragma unroll
        for (int kc = 0; kc < 8; ++kc) {
            unsigned wA[4] = {(unsigned)v[kc][0], (unsigned)v[kc][1],
                              (unsigned)v[kc][2], (unsigned)v[kc][3]};
            unsigned wB[4] = {(unsigned)v[kc + 8][0], (unsigned)v[kc + 8][1],
                              (unsigned)v[kc + 8][2], (unsigned)v[kc + 8][3]};
            half8 bfrA, bfrB;
            __builtin_memcpy(&bfrA, wA, 16);
            __builtin_memcpy(&bfrB, wB, 16);
            a0a = __builtin_amdgcn_mfma_f32_16x16x32_f16(wf0[kc],     bfrA, a0a, 0, 0, 0);
            a0b = __builtin_amdgcn_mfma_f32_16x16x32_f16(wf0[kc + 8], bfrB, a0b, 0, 0, 0);
            a1a = __builtin_amdgcn_mfma_f32_16x16x32_f16(wf1[kc],     bfrA, a1a, 0, 0, 0);
            a1b = __builtin_amdgcn_mfma_f32_16x16x32_f16(wf1[kc + 8], bfrB, a1b, 0, 0, 0);
        }

        // add prefetched xg, exchange i/f and g/o halves across lane^32
        float p0[4], p1[4];
#pragma unroll
        for (int r = 0; r < 4; ++r) {
            p0[r] = a0a[r] + a0b[r] + xp0[r];
            p1[r] = a1a[r] + a1b[r] + xp1[r];
        }
        float e0[4], e1[4];
#pragma unroll
        for (int r = 0; r < 4; ++r) {
            e0[r] = __shfl_xor(p0[r], 32);
            e1[r] = __shfl_xor(p1[r], 32);
        }
#pragma unroll
        for (int r = 0; r < 4; ++r) {
            float iv = (quad < 2) ? p0[r] : e0[r];
            float fv = (quad < 2) ? e0[r] : p0[r];
            float gv = (quad < 2) ? p1[r] : e1[r];
            float ov = (quad < 2) ? e1[r] : p1[r];
            float ii = 1.f / (1.f + __expf(-iv));
            float ff = 1.f / (1.f + __expf(-fv));
            float eg = __expf(-2.f * gv);
            float gg = (1.f - eg) / (1.f + eg);
            float oo = 1.f / (1.f + __expf(-ov));
            float cn = ff * c[r] + ii * gg;
            c[r] = cn;
            float ec = __expf(-2.f * cn);
            hh[r] = oo * ((1.f - ec) / (1.f + ec));
        }

        // ---- publish FIRST (critical path): 2 fire-and-forget u64 stores
        if (quad < 2) {
            _Float16 a01[2] = {(_Float16)hh[0], (_Float16)hh[1]};
            _Float16 a23[2] = {(_Float16)hh[2], (_Float16)hh[3]};
            unsigned lo0, lo1;
            __builtin_memcpy(&lo0, a01, 4);
            __builtin_memcpy(&lo1, a23, 4);
            const unsigned long long tagw = (unsigned long long)(t + 2) << 32;
            __hip_atomic_store(rnxt + mybase,     (unsigned long long)lo0 | tagw,
                               __ATOMIC_RELAXED, __HIP_MEMORY_SCOPE_AGENT);
            __hip_atomic_store(rnxt + mybase + 1, (unsigned long long)lo1 | tagw,
                               __ATOMIC_RELAXED, __HIP_MEMORY_SCOPE_AGENT);
            // out store: plain cached, off the exchange path
            *(float4*)(out + ((size_t)bglob * T + t) * H + hbase + (quad & 1) * 4) =
                make_float4(hh[0], hh[1], hh[2], hh[3]);
        }

        // xg(t+1): issue AND retire before the next spin (keeps rounds clean)
        if (t + 1 < T) {
            const _Float16* xgt = xg + (size_t)(t + 1) * G * B;
#pragma unroll
            for (int r = 0; r < 4; ++r) {
                xp0[r] = (float)xgt[(size_t)xrow0[r] * B + bglob];
                xp1[r] = (float)xgt[(size_t)xrow1[r] * B + bglob];
            }
            asm volatile("" : "+v"(xp0[0]), "+v"(xp0[1]), "+v"(xp0[2]), "+v"(xp0[3]),
                              "+v"(xp1[0]), "+v"(xp1[1]), "+v"(xp1[2]), "+v"(xp1[3]) :: "memory");
        }
    }

    // final h_T, c_T
    if (quad < 2) {
        float* hT = out + (size_t)B * T * H;
        float* cT = hT + (size_t)B * H;
#pragma unroll
        for (int r = 0; r < 4; ++r) {
            int jj = (quad & 1) * 4 + r;
            hT[(size_t)bglob * H + hbase + jj] = hh[r];
            cT[(size_t)bglob * H + hbase + jj] = c[r];
        }
    }
}

// ---------------------------------------------------------------------------
extern "C" void kernel_launch(void* const* d_in, const int* in_sizes, int n_in,
                              void* d_out, int out_size, void* d_ws, size_t ws_size,
                              hipStream_t stream) {
    const float* x    = (const float*)d_in[0];
    const float* h0   = (const float*)d_in[1];
    const float* c0   = (const float*)d_in[2];
    const float* W_ih = (const float*)d_in[3];
    const float* W_hh = (const float*)d_in[4];
    const float* b_ih = (const float*)d_in[5];
    const float* b_hh = (const float*)d_in[6];
    float* out = (float*)d_out;

    // workspace layout:
    //   [0, 256KiB)        : tagged h records [2][4][16][256] u64, zeroed
    //   [256KiB, +T*G*B*2) : xg (f16), 128 MiB
    constexpr size_t REC_BYTES = (size_t)2 * 4 * 16 * 256 * 8; // 262144
    unsigned long long* rec = (unsigned long long*)d_ws;
    _Float16* xg = (_Float16*)((char*)d_ws + REC_BYTES);

    hipMemsetAsync(d_ws, 0, REC_BYTES, stream);

    xg_gemm<<<dim3(16, 128), 256, 0, stream>>>(x, W_ih, b_ih, b_hh, xg);
    lstm_rec<<<64, 256, 0, stream>>>(h0, c0, W_hh, xg, rec, out);
}